// Round 1
// baseline (75526.617 us; speedup 1.0000x reference)
//
#include <hip/hip_runtime.h>
#include <math.h>

#define B_ 64
#define G_ 640
#define D_ 256
#define H_ 8
#define DH_ 32
#define NEG_INF_F (-1e9f)

__device__ __constant__ float INV_SQRT_DH = 0.17677669529663687f; // 1/sqrt(32)
__device__ __constant__ float INV_SQRT_D  = 0.0625f;              // 1/sqrt(256)

// ---------------------------------------------------------------------------
// K1: graph_embed (mean over G), fixed_ctx = ge @ W_fixed, q0 = fixed_ctx + ge @ W_step
// grid 64 blocks (one per b), 256 threads (one per d)
// ---------------------------------------------------------------------------
__global__ __launch_bounds__(256) void precompute_ctx(
    const float* __restrict__ emb, const float* __restrict__ W_fixed,
    const float* __restrict__ W_step, float* __restrict__ fixed_ctx,
    float* __restrict__ q0)
{
  const int b = blockIdx.x, d = threadIdx.x;
  __shared__ float ge[D_];
  const float* eb = emb + (size_t)b * G_ * D_;
  float s = 0.f;
  for (int g = 0; g < G_; ++g) s += eb[(size_t)g * D_ + d];
  ge[d] = s * (1.0f / (float)G_);
  __syncthreads();
  float fc = 0.f, qq = 0.f;
  for (int k = 0; k < D_; ++k) {
    const float gk = ge[k];
    fc = fmaf(gk, W_fixed[k * D_ + d], fc);
    qq = fmaf(gk, W_step[k * D_ + d], qq);
  }
  fixed_ctx[b * D_ + d] = fc;
  q0[b * D_ + d] = fc + qq;
}

// ---------------------------------------------------------------------------
// K0: Bmat [256 x 1024] = [ W_node(gk) | W_node(gv) | Wc = W_node3 @ W_out^T | W_step ]
// grid 256 blocks (one per k), 256 threads
// ---------------------------------------------------------------------------
__global__ __launch_bounds__(256) void build_bmat(
    const float* __restrict__ W_node, const float* __restrict__ W_step,
    const float* __restrict__ W_out, float* __restrict__ Bmat)
{
  const int k = blockIdx.x, t = threadIdx.x;
  __shared__ float wn3[D_];
  wn3[t] = W_node[k * 768 + 512 + t];
  __syncthreads();
  Bmat[k * 1024 + t]       = W_node[k * 768 + t];
  Bmat[k * 1024 + 256 + t] = W_node[k * 768 + 256 + t];
  float acc = 0.f;
  for (int j = 0; j < D_; ++j) acc = fmaf(wn3[j], W_out[t * D_ + j], acc);
  Bmat[k * 1024 + 512 + t] = acc;
  Bmat[k * 1024 + 768 + t] = W_step[k * D_ + t];
}

// ---------------------------------------------------------------------------
// K2: C[40960 x 1024] = emb[40960 x 256] @ Bmat[256 x 1024], scatter epilogue to
//   gkT[b][h][d][g], gv[b][h][g][d], lk2T[b][d][g], q_all[b][g][d] (+fixed_ctx)
// 128x128 tiles, 256 threads, 8x8 micro-tile.
// ---------------------------------------------------------------------------
__global__ __launch_bounds__(256) void gemm_scatter(
    const float* __restrict__ A, const float* __restrict__ Bm,
    const float* __restrict__ fixed_ctx,
    float* __restrict__ gkT, float* __restrict__ gv,
    float* __restrict__ lk2T, float* __restrict__ q_all)
{
  __shared__ float As[16][132];
  __shared__ float Bs[16][132];
  const int tid = threadIdx.x;
  const int bm = blockIdx.x;   // 320
  const int bn = blockIdx.y;   // 8
  const int tr = tid / 16, tc = tid % 16;
  const int row0 = bm * 128, col0 = bn * 128;
  float acc[8][8];
#pragma unroll
  for (int i = 0; i < 8; ++i)
#pragma unroll
    for (int j = 0; j < 8; ++j) acc[i][j] = 0.f;

  for (int k0 = 0; k0 < D_; k0 += 16) {
#pragma unroll
    for (int s = tid; s < 512; s += 256) {
      const int r = s >> 2, c4 = (s & 3) * 4;
      const float4 v = *(const float4*)&A[(size_t)(row0 + r) * D_ + k0 + c4];
      As[c4 + 0][r] = v.x; As[c4 + 1][r] = v.y;
      As[c4 + 2][r] = v.z; As[c4 + 3][r] = v.w;
    }
#pragma unroll
    for (int s = tid; s < 512; s += 256) {
      const int r = s >> 5, c4 = (s & 31) * 4;
      *(float4*)&Bs[r][c4] = *(const float4*)&Bm[(size_t)(k0 + r) * 1024 + col0 + c4];
    }
    __syncthreads();
#pragma unroll
    for (int kk = 0; kk < 16; ++kk) {
      float a[8], bfr[8];
#pragma unroll
      for (int i = 0; i < 8; ++i) a[i] = As[kk][tr * 8 + i];
#pragma unroll
      for (int j = 0; j < 8; ++j) bfr[j] = Bs[kk][tc * 8 + j];
#pragma unroll
      for (int i = 0; i < 8; ++i)
#pragma unroll
        for (int j = 0; j < 8; ++j) acc[i][j] = fmaf(a[i], bfr[j], acc[i][j]);
    }
    __syncthreads();
  }

#pragma unroll
  for (int i = 0; i < 8; ++i) {
    const int row = row0 + tr * 8 + i;
    const int bb = row / G_;
    const int g = row - bb * G_;
#pragma unroll
    for (int j = 0; j < 8; ++j) {
      const int n = col0 + tc * 8 + j;
      const float v = acc[i][j];
      if (n < 256) {
        const int h = n >> 5, d = n & 31;
        gkT[(((size_t)bb * H_ + h) * DH_ + d) * G_ + g] = v;
      } else if (n < 512) {
        const int m2 = n - 256, h = m2 >> 5, d = m2 & 31;
        gv[(((size_t)bb * H_ + h) * G_ + g) * DH_ + d] = v;
      } else if (n < 768) {
        const int d = n - 512;
        lk2T[((size_t)bb * D_ + d) * G_ + g] = v;
      } else {
        const int d = n - 768;
        q_all[((size_t)(bb * G_ + g)) * D_ + d] = v + fixed_ctx[bb * D_ + d];
      }
    }
  }
}

// ---------------------------------------------------------------------------
// K3: persistent decode. grid 64 blocks (one per b), 1024 threads, loop T steps.
// ---------------------------------------------------------------------------
__global__ __launch_bounds__(1024) void step_kernel(
    const float* __restrict__ gkT, const float* __restrict__ gv,
    const float* __restrict__ lk2T, const float* __restrict__ q_all,
    const float* __restrict__ q0, const int* __restrict__ n_steps_p,
    float* __restrict__ out)
{
  const int b = blockIdx.x;
  const int t = threadIdx.x;
  const int T = *n_steps_p;
  float* out_logp = out;                          // [B][T][G]
  float* out_pi = out + (size_t)B_ * T * G_;      // [B][T] (stored as float)

  __shared__ float q_s[D_];
  __shared__ float attn_s[H_][G_];
  __shared__ float heads_part[4][D_];
  __shared__ float heads_s[D_];
  __shared__ float logits_s[G_];
  __shared__ int   visited_s[G_];
  __shared__ float hmax_s[H_], hsum_s[H_];
  __shared__ float wred_v[16];
  __shared__ int   wred_i[16];
  __shared__ float wred_s[16];
  __shared__ float red_max;
  __shared__ float lse_s;
  __shared__ int   cur_sel;

  for (int g = t; g < G_; g += 1024) visited_s[g] = 0;

  const int h128 = t >> 7;   // head group for phase 2 (8 groups x 128 threads)
  const int j128 = t & 127;
  const int lane = t & 63;
  const int wave = t >> 6;

  for (int step = 0; step < T; ++step) {
    // ---- Phase 1: q = (step==0) ? q0[b] : q_all[b, prev_sel] ----
    int ps = 0;
    if (step > 0) ps = cur_sel;
    const float* qsrc = (step == 0) ? (q0 + (size_t)b * D_)
                                    : (q_all + ((size_t)b * G_ + ps) * D_);
    if (t < D_) q_s[t] = qsrc[t];
    __syncthreads();

    // ---- Phase 2a: compat[h][g] + mask, per-head max ----
    float cval[5];
    {
      const float* gk_b = gkT + ((size_t)b * H_ + h128) * DH_ * G_;
      float qreg[DH_];
#pragma unroll
      for (int d = 0; d < DH_; ++d) qreg[d] = q_s[h128 * DH_ + d];
      float lmax = NEG_INF_F;
#pragma unroll
      for (int r = 0; r < 5; ++r) {
        const int g = j128 + r * 128;
        float a0 = 0.f;
#pragma unroll
        for (int d = 0; d < DH_; ++d) a0 = fmaf(qreg[d], gk_b[(size_t)d * G_ + g], a0);
        float c = a0 * INV_SQRT_DH;
        if (visited_s[g]) c = NEG_INF_F;
        cval[r] = c;
        lmax = fmaxf(lmax, c);
      }
#pragma unroll
      for (int off = 32; off; off >>= 1) lmax = fmaxf(lmax, __shfl_down(lmax, off));
      if (lane == 0) wred_v[wave] = lmax;
    }
    __syncthreads();
    if (t < H_) hmax_s[t] = fmaxf(wred_v[2 * t], wred_v[2 * t + 1]);
    __syncthreads();

    // ---- Phase 2b: e = exp(c - max), per-head sum ----
    {
      const float hm = hmax_s[h128];
      float lsum = 0.f;
#pragma unroll
      for (int r = 0; r < 5; ++r) {
        const int g = j128 + r * 128;
        const float e = expf(cval[r] - hm);   // masked -> exp(-1e9-...) = 0
        attn_s[h128][g] = e;
        lsum += e;
      }
#pragma unroll
      for (int off = 32; off; off >>= 1) lsum += __shfl_down(lsum, off);
      if (lane == 0) wred_s[wave] = lsum;
    }
    __syncthreads();
    if (t < H_) hsum_s[t] = wred_s[2 * t] + wred_s[2 * t + 1];

    // ---- Phase 3: heads[h][d] = sum_g e[h][g] * gv[b,h,g,d], 4-way g-split ----
    {
      const int outp = t & 255;
      const int part = t >> 8;
      const int h = outp >> 5, d = outp & 31;
      const float* gv_b = gv + (((size_t)b * H_ + h) * G_) * DH_ + d;
      const float* arow = attn_s[h];
      float p = 0.f;
      const int g0 = part * 160;
#pragma unroll 4
      for (int g = g0; g < g0 + 160; ++g) p = fmaf(arow[g], gv_b[(size_t)g * DH_], p);
      heads_part[part][outp] = p;
    }
    __syncthreads();
    if (t < D_) {
      heads_s[t] = (heads_part[0][t] + heads_part[1][t] +
                    heads_part[2][t] + heads_part[3][t]) / hsum_s[t >> 5];
    }
    __syncthreads();

    // ---- Phase 4: logits[g] = 10*tanh(inv_sqrt_D * heads . lk2T[b,:,g]), mask ----
    if (t < G_) {
      const float* lk_b = lk2T + ((size_t)b * D_) * G_ + t;
      float a0 = 0.f;
#pragma unroll 8
      for (int d = 0; d < D_; ++d) a0 = fmaf(heads_s[d], lk_b[(size_t)d * G_], a0);
      float lg = 10.0f * tanhf(a0 * INV_SQRT_D);
      if (visited_s[t]) lg = NEG_INF_F;
      logits_s[t] = lg;
    }
    __syncthreads();

    // ---- Phase 5a: argmax (first-max tie-break) ----
    {
      float v = (t < G_) ? logits_s[t] : -INFINITY;
      int vi = t;
#pragma unroll
      for (int off = 32; off; off >>= 1) {
        const float ov = __shfl_down(v, off);
        const int oi = __shfl_down(vi, off);
        if (ov > v || (ov == v && oi < vi)) { v = ov; vi = oi; }
      }
      if (lane == 0) { wred_v[wave] = v; wred_i[wave] = vi; }
    }
    __syncthreads();
    if (t == 0) {
      float mv = wred_v[0]; int mi = wred_i[0];
      for (int w = 1; w < 16; ++w) {
        const float ov = wred_v[w]; const int oi = wred_i[w];
        if (ov > mv || (ov == mv && oi < mi)) { mv = ov; mi = oi; }
      }
      red_max = mv;
      cur_sel = mi;
      visited_s[mi] = 1;
      out_pi[(size_t)b * T + step] = (float)mi;
    }
    __syncthreads();

    // ---- Phase 5b: logsumexp ----
    {
      const float mv = red_max;
      float e = (t < G_) ? expf(logits_s[t] - mv) : 0.f;
#pragma unroll
      for (int off = 32; off; off >>= 1) e += __shfl_down(e, off);
      if (lane == 0) wred_s[wave] = e;
    }
    __syncthreads();
    if (t == 0) {
      float ssum = 0.f;
      for (int w = 0; w < 16; ++w) ssum += wred_s[w];
      lse_s = red_max + logf(ssum);
    }
    __syncthreads();

    if (t < G_) out_logp[((size_t)b * T + step) * G_ + t] = logits_s[t] - lse_s;
    // next iteration's phases are sync-protected before any conflicting LDS write
  }
}

// ---------------------------------------------------------------------------
extern "C" void kernel_launch(void* const* d_in, const int* in_sizes, int n_in,
                              void* d_out, int out_size, void* d_ws, size_t ws_size,
                              hipStream_t stream)
{
  const float* emb     = (const float*)d_in[0];
  const float* W_node  = (const float*)d_in[1];
  const float* W_fixed = (const float*)d_in[2];
  const float* W_step  = (const float*)d_in[3];
  const float* W_out   = (const float*)d_in[4];
  const int*   n_steps = (const int*)d_in[5];

  float* ws = (float*)d_ws;
  float* fixed_ctx = ws;                               // 64*256
  float* q0        = fixed_ctx + B_ * D_;              // 64*256
  float* Bmat      = q0 + B_ * D_;                     // 256*1024
  float* gkT       = Bmat + D_ * 1024;                 // 64*8*32*640
  float* gv        = gkT + (size_t)B_ * D_ * G_;       // 64*8*640*32
  float* lk2T      = gv + (size_t)B_ * D_ * G_;        // 64*256*640
  float* q_all     = lk2T + (size_t)B_ * D_ * G_;      // 64*640*256

  precompute_ctx<<<B_, 256, 0, stream>>>(emb, W_fixed, W_step, fixed_ctx, q0);
  build_bmat<<<D_, 256, 0, stream>>>(W_node, W_step, W_out, Bmat);
  gemm_scatter<<<dim3(320, 8), 256, 0, stream>>>(emb, Bmat, fixed_ctx,
                                                 gkT, gv, lk2T, q_all);
  step_kernel<<<B_, 1024, 0, stream>>>(gkT, gv, lk2T, q_all, q0, n_steps,
                                       (float*)d_out);
}

// Round 2
// 18140.842 us; speedup vs baseline: 4.1633x; 4.1633x over previous
//
#include <hip/hip_runtime.h>
#include <math.h>

#define B_ 64
#define G_ 640
#define D_ 256
#define H_ 8
#define DH_ 32
#define NBLK 4
#define GS 160            // G_/NBLK
#define NEG_INF_F (-1e9f)

__device__ __constant__ float INV_SQRT_DH = 0.17677669529663687f; // 1/sqrt(32)
__device__ __constant__ float INV_SQRT_D  = 0.0625f;              // 1/sqrt(256)

// ---------------------------------------------------------------------------
// K1: graph_embed (mean over G), fixed_ctx = ge @ W_fixed, q0 = fixed_ctx + ge @ W_step
// ---------------------------------------------------------------------------
__global__ __launch_bounds__(256) void precompute_ctx(
    const float* __restrict__ emb, const float* __restrict__ W_fixed,
    const float* __restrict__ W_step, float* __restrict__ fixed_ctx,
    float* __restrict__ q0)
{
  const int b = blockIdx.x, d = threadIdx.x;
  __shared__ float ge[D_];
  const float* eb = emb + (size_t)b * G_ * D_;
  float s = 0.f;
  for (int g = 0; g < G_; ++g) s += eb[(size_t)g * D_ + d];
  ge[d] = s * (1.0f / (float)G_);
  __syncthreads();
  float fc = 0.f, qq = 0.f;
  for (int k = 0; k < D_; ++k) {
    const float gk = ge[k];
    fc = fmaf(gk, W_fixed[k * D_ + d], fc);
    qq = fmaf(gk, W_step[k * D_ + d], qq);
  }
  fixed_ctx[b * D_ + d] = fc;
  q0[b * D_ + d] = fc + qq;
}

// ---------------------------------------------------------------------------
// K0: Bmat [256 x 1024] = [ gk | gv | Wc = W_node3 @ W_out^T | W_step ]
// ---------------------------------------------------------------------------
__global__ __launch_bounds__(256) void build_bmat(
    const float* __restrict__ W_node, const float* __restrict__ W_step,
    const float* __restrict__ W_out, float* __restrict__ Bmat)
{
  const int k = blockIdx.x, t = threadIdx.x;
  __shared__ float wn3[D_];
  wn3[t] = W_node[k * 768 + 512 + t];
  __syncthreads();
  Bmat[k * 1024 + t]       = W_node[k * 768 + t];
  Bmat[k * 1024 + 256 + t] = W_node[k * 768 + 256 + t];
  float acc = 0.f;
  for (int j = 0; j < D_; ++j) acc = fmaf(wn3[j], W_out[t * D_ + j], acc);
  Bmat[k * 1024 + 512 + t] = acc;
  Bmat[k * 1024 + 768 + t] = W_step[k * D_ + t];
}

// ---------------------------------------------------------------------------
// K2: C[40960 x 1024] = emb @ Bmat, scatter to gkT/gv/lk2T/q_all
// ---------------------------------------------------------------------------
__global__ __launch_bounds__(256) void gemm_scatter(
    const float* __restrict__ A, const float* __restrict__ Bm,
    const float* __restrict__ fixed_ctx,
    float* __restrict__ gkT, float* __restrict__ gv,
    float* __restrict__ lk2T, float* __restrict__ q_all)
{
  __shared__ float As[16][132];
  __shared__ float Bs[16][132];
  const int tid = threadIdx.x;
  const int bm = blockIdx.x;   // 320
  const int bn = blockIdx.y;   // 8
  const int tr = tid / 16, tc = tid % 16;
  const int row0 = bm * 128, col0 = bn * 128;
  float acc[8][8];
#pragma unroll
  for (int i = 0; i < 8; ++i)
#pragma unroll
    for (int j = 0; j < 8; ++j) acc[i][j] = 0.f;

  for (int k0 = 0; k0 < D_; k0 += 16) {
#pragma unroll
    for (int s = tid; s < 512; s += 256) {
      const int r = s >> 2, c4 = (s & 3) * 4;
      const float4 v = *(const float4*)&A[(size_t)(row0 + r) * D_ + k0 + c4];
      As[c4 + 0][r] = v.x; As[c4 + 1][r] = v.y;
      As[c4 + 2][r] = v.z; As[c4 + 3][r] = v.w;
    }
#pragma unroll
    for (int s = tid; s < 512; s += 256) {
      const int r = s >> 5, c4 = (s & 31) * 4;
      *(float4*)&Bs[r][c4] = *(const float4*)&Bm[(size_t)(k0 + r) * 1024 + col0 + c4];
    }
    __syncthreads();
#pragma unroll
    for (int kk = 0; kk < 16; ++kk) {
      float a[8], bfr[8];
#pragma unroll
      for (int i = 0; i < 8; ++i) a[i] = As[kk][tr * 8 + i];
#pragma unroll
      for (int j = 0; j < 8; ++j) bfr[j] = Bs[kk][tc * 8 + j];
#pragma unroll
      for (int i = 0; i < 8; ++i)
#pragma unroll
        for (int j = 0; j < 8; ++j) acc[i][j] = fmaf(a[i], bfr[j], acc[i][j]);
    }
    __syncthreads();
  }

#pragma unroll
  for (int i = 0; i < 8; ++i) {
    const int row = row0 + tr * 8 + i;
    const int bb = row / G_;
    const int g = row - bb * G_;
#pragma unroll
    for (int j = 0; j < 8; ++j) {
      const int n = col0 + tc * 8 + j;
      const float v = acc[i][j];
      if (n < 256) {
        const int h = n >> 5, d = n & 31;
        gkT[(((size_t)bb * H_ + h) * DH_ + d) * G_ + g] = v;
      } else if (n < 512) {
        const int m2 = n - 256, h = m2 >> 5, d = m2 & 31;
        gv[(((size_t)bb * H_ + h) * G_ + g) * DH_ + d] = v;
      } else if (n < 768) {
        const int d = n - 512;
        lk2T[((size_t)bb * D_ + d) * G_ + g] = v;
      } else {
        const int d = n - 768;
        q_all[((size_t)(bb * G_ + g)) * D_ + d] = v + fixed_ctx[bb * D_ + d];
      }
    }
  }
}

// ---------------------------------------------------------------------------
// K3: sliced decode. 256 blocks = 64 b x 4 slices, 1024 threads.
// Cross-block sync (4 blocks per b) via device-scope counter barrier.
// ---------------------------------------------------------------------------
__global__ __launch_bounds__(1024) void step_sliced(
    const float* __restrict__ gkT, const float* __restrict__ gv,
    const float* __restrict__ lk2T, const float* __restrict__ q_all,
    const float* __restrict__ q0, const int* __restrict__ n_steps_p,
    float* __restrict__ comm1, float* __restrict__ comm2,
    unsigned int* __restrict__ bar, float* __restrict__ out)
{
  const int b   = blockIdx.x >> 2;
  const int blk = blockIdx.x & 3;
  const int t   = threadIdx.x;
  const int T   = *n_steps_p;
  const int g0  = blk * GS;
  float* out_logp = out;                          // [B][T][G]
  float* out_pi   = out + (size_t)B_ * T * G_;    // [B][T]

  __shared__ float q_s[D_];
  __shared__ float attn_s[H_][GS];
  __shared__ float hpart[4][D_];
  __shared__ float hsum_part[4][H_];
  __shared__ float heads_s[D_];
  __shared__ float hsum_s[H_];
  __shared__ float logits_s[GS];
  __shared__ float lpart[4][GS];
  __shared__ int   vis[GS];
  __shared__ float redv[4]; __shared__ int redi[4]; __shared__ float reds[4];
  __shared__ int   sel_s;
  __shared__ float lse_s;

  for (int i = t; i < GS; i += 1024) vis[i] = 0;
  if (t == 0) sel_s = 0;
  __syncthreads();

  unsigned int* mybar = bar + b * 32;
  float* c1 = comm1 + (size_t)b * NBLK * 264;
  float* c2 = comm2 + (size_t)b * NBLK * 4;

  const int lane = t & 63;
  const int wave = t >> 6;

  for (int step = 0; step < T; ++step) {
    // ---- q load ----
    const float* qsrc = (step == 0) ? (q0 + (size_t)b * D_)
                                    : (q_all + ((size_t)b * G_ + sel_s) * D_);
    if (t < D_) q_s[t] = qsrc[t];
    __syncthreads();

    // ---- phase 2: e[h][gl] = exp(compat) (zero-shift), masked -> 0 ----
    for (int idx = t; idx < H_ * GS; idx += 1024) {
      const int h = idx / GS, gl = idx - h * GS;
      const float* gk = gkT + (((size_t)b * H_ + h) * DH_) * G_ + (g0 + gl);
      float a0 = 0.f;
#pragma unroll
      for (int d = 0; d < DH_; ++d) a0 = fmaf(q_s[h * DH_ + d], gk[(size_t)d * G_], a0);
      const float c = a0 * INV_SQRT_DH;
      attn_s[h][gl] = vis[gl] ? 0.f : expf(c);
    }
    __syncthreads();

    // ---- phase 3: partial heads over local slice ----
    {
      const int part = t >> 8;                 // 0..3
      const int hd = t & 255;
      const int h = hd >> 5, d = hd & 31;
      const float* gvb = gv + (((size_t)b * H_ + h) * G_ + g0) * DH_ + d;
      const float* arow = attn_s[h];
      float p = 0.f, se = 0.f;
      const int gA = part * 40;
#pragma unroll 4
      for (int g = gA; g < gA + 40; ++g) {
        const float e = arow[g];
        p = fmaf(e, gvb[(size_t)g * DH_], p);
        se += e;
      }
      hpart[part][hd] = p;
      if (d == 0) hsum_part[part][h] = se;
    }
    __syncthreads();
    if (t < 256) {
      const float s = hpart[0][t] + hpart[1][t] + hpart[2][t] + hpart[3][t];
      __hip_atomic_store(&c1[blk * 264 + t], s, __ATOMIC_RELAXED, __HIP_MEMORY_SCOPE_AGENT);
    } else if (t < 264) {
      const int h = t - 256;
      const float s = hsum_part[0][h] + hsum_part[1][h] + hsum_part[2][h] + hsum_part[3][h];
      __hip_atomic_store(&c1[blk * 264 + t], s, __ATOMIC_RELAXED, __HIP_MEMORY_SCOPE_AGENT);
    }
    __syncthreads();   // drains vmcnt: partial stores complete before arrive
    if (t == 0) {
      __hip_atomic_fetch_add(mybar, 1u, __ATOMIC_RELEASE, __HIP_MEMORY_SCOPE_AGENT);
      const unsigned tgt = (unsigned)step * 8u + 4u;
      while (__hip_atomic_load(mybar, __ATOMIC_ACQUIRE, __HIP_MEMORY_SCOPE_AGENT) < tgt)
        __builtin_amdgcn_s_sleep(2);
    }
    __syncthreads();

    // ---- combine heads across 4 blocks ----
    float hval = 0.f;
    if (t < 256) {
#pragma unroll
      for (int k = 0; k < NBLK; ++k)
        hval += __hip_atomic_load(&c1[k * 264 + t], __ATOMIC_RELAXED, __HIP_MEMORY_SCOPE_AGENT);
    } else if (t < 264) {
      float s = 0.f;
#pragma unroll
      for (int k = 0; k < NBLK; ++k)
        s += __hip_atomic_load(&c1[k * 264 + t], __ATOMIC_RELAXED, __HIP_MEMORY_SCOPE_AGENT);
      hsum_s[t - 256] = s;
    }
    __syncthreads();
    if (t < 256) heads_s[t] = hval / hsum_s[t >> 5];
    __syncthreads();

    // ---- phase 4: logits for local slice ----
    if (t < 640) {
      const int part = t / GS;                 // 0..3 (64 d's each)
      const int gl = t - part * GS;
      const float* lkb = lk2T + ((size_t)b * D_ + part * 64) * G_ + (g0 + gl);
      float a0 = 0.f;
#pragma unroll 8
      for (int d = 0; d < 64; ++d) a0 = fmaf(heads_s[part * 64 + d], lkb[(size_t)d * G_], a0);
      lpart[part][gl] = a0;
    }
    __syncthreads();

    float lval = -INFINITY, eval = 0.f;
    int gidx = 1 << 30;
    if (t < GS) {
      const float a = (lpart[0][t] + lpart[1][t] + lpart[2][t] + lpart[3][t]) * INV_SQRT_D;
      float lg = 10.0f * tanhf(a);
      if (vis[t]) lg = NEG_INF_F;
      logits_s[t] = lg;
      lval = lg; gidx = g0 + t;
      eval = expf(lg - 10.0f);                 // fixed shift; masked -> 0
    }
    if (t < 192) {
      float v = lval; int vi = gidx; float es = eval;
#pragma unroll
      for (int off = 32; off; off >>= 1) {
        const float ov = __shfl_down(v, off);
        const int oi = __shfl_down(vi, off);
        const float oe = __shfl_down(es, off);
        es += oe;
        if (ov > v || (ov == v && oi < vi)) { v = ov; vi = oi; }
      }
      if (lane == 0) { redv[wave] = v; redi[wave] = vi; reds[wave] = es; }
    }
    __syncthreads();
    if (t == 0) {
      float mv = redv[0]; int mi = redi[0]; float ss = reds[0];
      for (int w = 1; w < 3; ++w) {
        ss += reds[w];
        if (redv[w] > mv || (redv[w] == mv && redi[w] < mi)) { mv = redv[w]; mi = redi[w]; }
      }
      __hip_atomic_store(&c2[blk * 4 + 0], mv, __ATOMIC_RELAXED, __HIP_MEMORY_SCOPE_AGENT);
      __hip_atomic_store(&c2[blk * 4 + 1], __int_as_float(mi), __ATOMIC_RELAXED, __HIP_MEMORY_SCOPE_AGENT);
      __hip_atomic_store(&c2[blk * 4 + 2], ss, __ATOMIC_RELAXED, __HIP_MEMORY_SCOPE_AGENT);
    }
    __syncthreads();   // drain stores
    if (t == 0) {
      __hip_atomic_fetch_add(mybar, 1u, __ATOMIC_RELEASE, __HIP_MEMORY_SCOPE_AGENT);
      const unsigned tgt = (unsigned)step * 8u + 8u;
      while (__hip_atomic_load(mybar, __ATOMIC_ACQUIRE, __HIP_MEMORY_SCOPE_AGENT) < tgt)
        __builtin_amdgcn_s_sleep(2);
      // combine selection + lse
      float mv = -INFINITY; int mi = 1 << 30; float ss = 0.f;
#pragma unroll
      for (int k = 0; k < NBLK; ++k) {
        const float v = __hip_atomic_load(&c2[k * 4 + 0], __ATOMIC_RELAXED, __HIP_MEMORY_SCOPE_AGENT);
        const int vi = __float_as_int(__hip_atomic_load(&c2[k * 4 + 1], __ATOMIC_RELAXED, __HIP_MEMORY_SCOPE_AGENT));
        ss += __hip_atomic_load(&c2[k * 4 + 2], __ATOMIC_RELAXED, __HIP_MEMORY_SCOPE_AGENT);
        if (v > mv || (v == mv && vi < mi)) { mv = v; mi = vi; }
      }
      sel_s = mi;
      lse_s = 10.0f + logf(ss);
      if (mi >= g0 && mi < g0 + GS) vis[mi - g0] = 1;
      if (blk == 0) out_pi[(size_t)b * T + step] = (float)mi;
    }
    __syncthreads();

    if (t < GS) out_logp[((size_t)b * T + step) * G_ + (g0 + t)] = logits_s[t] - lse_s;
  }
}

// ---------------------------------------------------------------------------
extern "C" void kernel_launch(void* const* d_in, const int* in_sizes, int n_in,
                              void* d_out, int out_size, void* d_ws, size_t ws_size,
                              hipStream_t stream)
{
  const float* emb     = (const float*)d_in[0];
  const float* W_node  = (const float*)d_in[1];
  const float* W_fixed = (const float*)d_in[2];
  const float* W_step  = (const float*)d_in[3];
  const float* W_out   = (const float*)d_in[4];
  const int*   n_steps = (const int*)d_in[5];

  float* ws = (float*)d_ws;
  float* fixed_ctx = ws;                               // 16384
  float* q0        = fixed_ctx + B_ * D_;              // 16384
  float* Bmat      = q0 + B_ * D_;                     // 262144
  float* gkT       = Bmat + D_ * 1024;                 // 10.5M
  float* gv        = gkT + (size_t)B_ * D_ * G_;
  float* lk2T      = gv + (size_t)B_ * D_ * G_;
  float* q_all     = lk2T + (size_t)B_ * D_ * G_;
  float* comm1     = q_all + (size_t)B_ * G_ * D_;     // 64*4*264
  float* comm2     = comm1 + (size_t)B_ * NBLK * 264;  // 64*4*4
  unsigned int* bar = (unsigned int*)(comm2 + (size_t)B_ * NBLK * 4); // 64*32

  hipMemsetAsync(bar, 0, B_ * 32 * sizeof(unsigned int), stream);
  precompute_ctx<<<B_, 256, 0, stream>>>(emb, W_fixed, W_step, fixed_ctx, q0);
  build_bmat<<<D_, 256, 0, stream>>>(W_node, W_step, W_out, Bmat);
  gemm_scatter<<<dim3(320, 8), 256, 0, stream>>>(emb, Bmat, fixed_ctx,
                                                 gkT, gv, lk2T, q_all);
  step_sliced<<<B_ * NBLK, 1024, 0, stream>>>(gkT, gv, lk2T, q_all, q0, n_steps,
                                              comm1, comm2, bar, (float*)d_out);
}